// Round 2
// baseline (2281.066 us; speedup 1.0000x reference)
//
#include <hip/hip_runtime.h>

// VectorQuantizer: B=32768, K=8192, D=256, fp32.
// out layout (flat float): z_q [B*D], vq_loss [1], commit [1], indices-as-float [B]
// ws layout: idx_i int[B] | s_z float[B] | partial float[B/4]
//
// Numerics: replicate the reference's fp32 rounding structure.
//   ref dist = fl32( fl32(||z||^2 + ||e||^2) - fl32(2*dot) )
// Since ||e_k||^2 ~ 1.3e-6 << half-ulp(256) = 1.5e-5, fl32(S + ||e||^2) == S always,
// so dist_k = fl32(S - 2*fl32(dot_k)): quantized at ulp(256) ~ 3e-5, with frequent
// exact ties resolved by FIRST index. dot_k must be a single fp32 FMA chain
// ascending in d (matches BLAS sgemm microkernel accumulation order).

namespace {
constexpr int NB = 32768;
constexpr int NK = 8192;
constexpr int ND = 256;
constexpr int BM = 128;   // rows per block
constexpr int BN = 128;   // codes per chunk
constexpr int BK = 16;    // d per stage

// ---- S[row] = ||z_row||^2 (fp32; summation order irrelevant, see header) ----
__global__ void sz_kernel(const float* __restrict__ z, float* __restrict__ sz) {
  const int row = blockIdx.x * 4 + (threadIdx.x >> 6);
  const int lane = threadIdx.x & 63;
  const float4 v = reinterpret_cast<const float4*>(z)[(size_t)row * (ND / 4) + lane];
  float s = v.x * v.x + v.y * v.y + v.z * v.z + v.w * v.w;
#pragma unroll
  for (int off = 32; off; off >>= 1) s += __shfl_down(s, off, 64);
  if (lane == 0) sz[row] = s;
}

// ---- argmin over codes of fl32(S - 2*fl32(z.e)), first-index tie-break ----
__global__ __launch_bounds__(256, 1) void argmin_kernel(
    const float* __restrict__ z, const float* __restrict__ emb,
    const float* __restrict__ sz, int* __restrict__ idx_i,
    float* __restrict__ idx_f) {
  __shared__ float zT[ND][BM];     // 128 KB, persistent z^T tile
  __shared__ float eT[2][BK][BN];  // 16 KB, double-buffered e^T chunk

  const int tid = threadIdx.x;
  const int tx = tid & 15;
  const int ty = tid >> 4;
  const int row0 = blockIdx.x * BM;

  // stage zT (transpose z[row][d] -> zT[d][row]); one-time cost
  {
    const float4* z4 = reinterpret_cast<const float4*>(z) + (size_t)row0 * (ND / 4);
#pragma unroll
    for (int it = 0; it < 32; ++it) {
      int fi = it * 256 + tid;  // float4 index in tile (128 rows * 64 f4/row)
      int r = fi >> 6;
      int dq = fi & 63;
      float4 v = z4[(size_t)r * (ND / 4) + dq];
      zT[dq * 4 + 0][r] = v.x;
      zT[dq * 4 + 1][r] = v.y;
      zT[dq * 4 + 2][r] = v.z;
      zT[dq * 4 + 3][r] = v.w;
    }
  }

  float Srow[8];
#pragma unroll
  for (int i = 0; i < 8; ++i) Srow[i] = sz[row0 + ty * 8 + i];

  float best[8];
  int bidx[8];
#pragma unroll
  for (int i = 0; i < 8; ++i) { best[i] = 3.4e38f; bidx[i] = 0; }

  const float4* e4 = reinterpret_cast<const float4*>(emb);
  const int f0 = tid, f1 = tid + 256;         // each thread stages 2 float4 per dk
  const int cA = f0 >> 2, qA = f0 & 3;        // code-local, d-quarter
  const int cB = f1 >> 2, qB = f1 & 3;

  for (int n = 0; n < NK / BN; ++n) {
    const int c0 = n * BN;
    float acc[8][8];
#pragma unroll
    for (int i = 0; i < 8; ++i)
#pragma unroll
      for (int j = 0; j < 8; ++j) acc[i][j] = 0.f;

    // preload dk=0 into regs
    float4 p0 = e4[(size_t)(c0 + cA) * (ND / 4) + qA];
    float4 p1 = e4[(size_t)(c0 + cB) * (ND / 4) + qB];

    for (int dk = 0; dk < ND / BK; ++dk) {
      const int buf = dk & 1;
      // write staged regs into eT[buf] (transposed: eT[d_local][code])
      eT[buf][qA * 4 + 0][cA] = p0.x;
      eT[buf][qA * 4 + 1][cA] = p0.y;
      eT[buf][qA * 4 + 2][cA] = p0.z;
      eT[buf][qA * 4 + 3][cA] = p0.w;
      eT[buf][qB * 4 + 0][cB] = p1.x;
      eT[buf][qB * 4 + 1][cB] = p1.y;
      eT[buf][qB * 4 + 2][cB] = p1.z;
      eT[buf][qB * 4 + 3][cB] = p1.w;
      // prefetch next dk (latency hides under compute below)
      if (dk + 1 < ND / BK) {
        p0 = e4[(size_t)(c0 + cA) * (ND / 4) + (dk + 1) * 4 + qA];
        p1 = e4[(size_t)(c0 + cB) * (ND / 4) + (dk + 1) * 4 + qB];
      }
      __syncthreads();  // single barrier per dk; dbuf makes write-after-read safe
#pragma unroll
      for (int dd = 0; dd < BK; ++dd) {
        float za[8], eb[8];
#pragma unroll
        for (int i = 0; i < 8; ++i) za[i] = zT[dk * BK + dd][ty * 8 + i];
#pragma unroll
        for (int j = 0; j < 8; ++j) eb[j] = eT[buf][dd][tx * 8 + j];
        // single fp32 FMA chain per (row, code), ascending d — matches sgemm
#pragma unroll
        for (int i = 0; i < 8; ++i)
#pragma unroll
          for (int j = 0; j < 8; ++j) acc[i][j] = fmaf(za[i], eb[j], acc[i][j]);
      }
    }

    // running argmin update for this chunk: dist = fl32(S - 2*fl32(dot))
#pragma unroll
    for (int i = 0; i < 8; ++i)
#pragma unroll
      for (int j = 0; j < 8; ++j) {
        float dist = Srow[i] - 2.0f * acc[i][j];
        if (dist < best[i]) {  // strict < keeps earliest index (argmin semantics)
          best[i] = dist;
          bidx[i] = c0 + tx * 8 + j;
        }
      }
  }

  // reduce across the 16 tx lanes (same ty); prefer smaller index on exact ties
#pragma unroll
  for (int i = 0; i < 8; ++i) {
    float bv = best[i];
    int bi = bidx[i];
#pragma unroll
    for (int m = 1; m < 16; m <<= 1) {
      float ov = __shfl_xor(bv, m, 64);
      int oi = __shfl_xor(bi, m, 64);
      if (ov < bv || (ov == bv && oi < bi)) { bv = ov; bi = oi; }
    }
    if (tx == 0) {
      int row = row0 + ty * 8 + i;
      idx_i[row] = bi;
      idx_f[row] = (float)bi;
    }
  }
}

// ---- gather z_q = emb[idx], partial sums of (z_q - z)^2 ----
__global__ void gather_kernel(const float* __restrict__ z,
                              const float* __restrict__ emb,
                              const int* __restrict__ idx,
                              float* __restrict__ zq,
                              float* __restrict__ partial) {
  const int w = threadIdx.x >> 6;
  const int lane = threadIdx.x & 63;
  const int row = blockIdx.x * 4 + w;
  const int k = idx[row];
  const float4 e = reinterpret_cast<const float4*>(emb)[(size_t)k * (ND / 4) + lane];
  const float4 zv = reinterpret_cast<const float4*>(z)[(size_t)row * (ND / 4) + lane];
  reinterpret_cast<float4*>(zq)[(size_t)row * (ND / 4) + lane] = e;
  const float dx = e.x - zv.x, dy = e.y - zv.y, dz = e.z - zv.z, dw = e.w - zv.w;
  float s = dx * dx + dy * dy + dz * dz + dw * dw;
#pragma unroll
  for (int off = 32; off; off >>= 1) s += __shfl_down(s, off, 64);
  __shared__ float sm[4];
  if (lane == 0) sm[w] = s;
  __syncthreads();
  if (threadIdx.x == 0) partial[blockIdx.x] = sm[0] + sm[1] + sm[2] + sm[3];
}

// ---- deterministic final loss reduction ----
__global__ void loss_kernel(const float* __restrict__ partial, int n,
                            float* __restrict__ out_loss) {
  double s = 0.0;
  for (int i = threadIdx.x; i < n; i += 256) s += (double)partial[i];
  __shared__ double sm[256];
  sm[threadIdx.x] = s;
  __syncthreads();
  for (int st = 128; st; st >>= 1) {
    if (threadIdx.x < st) sm[threadIdx.x] += sm[threadIdx.x + st];
    __syncthreads();
  }
  if (threadIdx.x == 0) {
    float loss = (float)(0.25 * sm[0] / (double)((size_t)NB * ND));
    out_loss[0] = loss;  // vq_loss
    out_loss[1] = loss;  // commitment loss (same forward value)
  }
}

}  // namespace

extern "C" void kernel_launch(void* const* d_in, const int* in_sizes, int n_in,
                              void* d_out, int out_size, void* d_ws, size_t ws_size,
                              hipStream_t stream) {
  const float* z = (const float*)d_in[0];
  const float* emb = (const float*)d_in[1];
  float* out = (float*)d_out;
  float* zq = out;
  float* loss = out + (size_t)NB * ND;
  float* idx_f = out + (size_t)NB * ND + 2;

  int* idx_i = (int*)d_ws;
  float* sz = (float*)((char*)d_ws + (size_t)NB * 4);
  float* partial = (float*)((char*)d_ws + (size_t)NB * 4 * 2);

  sz_kernel<<<NB / 4, 256, 0, stream>>>(z, sz);
  argmin_kernel<<<NB / BM, 256, 0, stream>>>(z, emb, sz, idx_i, idx_f);
  gather_kernel<<<NB / 4, 256, 0, stream>>>(z, emb, idx_i, zq, partial);
  loss_kernel<<<1, 256, 0, stream>>>(partial, NB / 4, loss);
}

// Round 3
// 1808.406 us; speedup vs baseline: 1.2614x; 1.2614x over previous
//
#include <hip/hip_runtime.h>

// VectorQuantizer: B=32768, K=8192, D=256, fp32.
// out layout (flat float): z_q [B*D], vq_loss [1], commit [1], indices-as-float [B]
// ws layout: idx_i int[B] | s_z float[B] | partial float[B/4]
//
// Numerics (verified round 2): ref dist = fl32(S - 2*fl32(dot)), dot = single
// fp32 FMA chain ascending in d per (row,code); ties (frequent — dist is
// quantized at ulp(||z||^2~256) = 3e-5) resolved by FIRST index.
//
// argmin_kernel geometry:
//   block = 256 threads (tx = tid&31 codes, ty = tid>>5 rows), BM=64 rows,
//   BN=512 codes/chunk, BK=4 d/stage. Per-thread tile 8 rows x 16 codes.
//   LDS: zT[256][64] (64KB) + eT[2][4][512] (16KB) = 80KB -> 2 blocks/CU.
//   Reads per dd: za 2x b128 (broadcast, conflict-free) + eb 4x b128
//   (16B-stride across lanes -> 2-way = free) per 128 FMA.

namespace {
constexpr int NB = 32768;
constexpr int NK = 8192;
constexpr int ND = 256;
constexpr int BM = 64;    // rows per block
constexpr int BN = 512;   // codes per chunk
constexpr int BK = 4;     // d per stage

// ---- S[row] = ||z_row||^2 ----
__global__ void sz_kernel(const float* __restrict__ z, float* __restrict__ sz) {
  const int row = blockIdx.x * 4 + (threadIdx.x >> 6);
  const int lane = threadIdx.x & 63;
  const float4 v = reinterpret_cast<const float4*>(z)[(size_t)row * (ND / 4) + lane];
  float s = v.x * v.x + v.y * v.y + v.z * v.z + v.w * v.w;
#pragma unroll
  for (int off = 32; off; off >>= 1) s += __shfl_down(s, off, 64);
  if (lane == 0) sz[row] = s;
}

// ---- argmin over codes of fl32(S - 2*fl32(z.e)), first-index tie-break ----
__global__ __launch_bounds__(256, 2) void argmin_kernel(
    const float* __restrict__ z, const float* __restrict__ emb,
    const float* __restrict__ sz, int* __restrict__ idx_i,
    float* __restrict__ idx_f) {
  __shared__ float zT[ND][BM];       // 64 KB, persistent z^T tile
  __shared__ float eT[2][BK][BN];    // 16 KB, double-buffered e^T chunk

  const int tid = threadIdx.x;
  const int tx = tid & 31;   // code group
  const int ty = tid >> 5;   // row group (0..7)
  const int row0 = blockIdx.x * BM;

  // stage zT (transpose z[row][d] -> zT[d][row]); coalesced loads, one-time
  {
    const float4* z4 = reinterpret_cast<const float4*>(z) + (size_t)row0 * (ND / 4);
#pragma unroll
    for (int it = 0; it < 16; ++it) {
      int fi = it * 256 + tid;  // float4 index in tile (64 rows * 64 f4/row)
      int r = fi >> 6;
      int dq = fi & 63;
      float4 v = z4[(size_t)r * (ND / 4) + dq];
      zT[dq * 4 + 0][r] = v.x;
      zT[dq * 4 + 1][r] = v.y;
      zT[dq * 4 + 2][r] = v.z;
      zT[dq * 4 + 3][r] = v.w;
    }
  }

  float Srow[8];
#pragma unroll
  for (int i = 0; i < 8; ++i) Srow[i] = sz[row0 + ty * 8 + i];

  float best[8];
  int bidx[8];
#pragma unroll
  for (int i = 0; i < 8; ++i) { best[i] = 3.4e38f; bidx[i] = 0; }

  const float4* e4 = reinterpret_cast<const float4*>(emb);
  const int cA = tid;        // stages code rows tid and tid+256
  const int cB = tid + 256;

  for (int n = 0; n < NK / BN; ++n) {
    const int c0 = n * BN;
    float acc[8][16];
#pragma unroll
    for (int i = 0; i < 8; ++i)
#pragma unroll
      for (int j = 0; j < 16; ++j) acc[i][j] = 0.f;

    // preload dk=0 slice (1 float4 per staged code row)
    float4 p0 = e4[(size_t)(c0 + cA) * (ND / 4) + 0];
    float4 p1 = e4[(size_t)(c0 + cB) * (ND / 4) + 0];

    for (int dk = 0; dk < ND / BK; ++dk) {
      const int buf = dk & 1;
      // transposed store: eT[dd][code]; lane-consecutive addresses -> no conflicts
      eT[buf][0][cA] = p0.x;
      eT[buf][1][cA] = p0.y;
      eT[buf][2][cA] = p0.z;
      eT[buf][3][cA] = p0.w;
      eT[buf][0][cB] = p1.x;
      eT[buf][1][cB] = p1.y;
      eT[buf][2][cB] = p1.z;
      eT[buf][3][cB] = p1.w;
      if (dk + 1 < ND / BK) {  // prefetch next slice; L2 retains the 64B lines
        p0 = e4[(size_t)(c0 + cA) * (ND / 4) + dk + 1];
        p1 = e4[(size_t)(c0 + cB) * (ND / 4) + dk + 1];
      }
      __syncthreads();  // dbuf: single barrier per stage is sufficient
#pragma unroll
      for (int dd = 0; dd < BK; ++dd) {
        const int d = dk * BK + dd;
        // za: 8 rows, broadcast across tx lanes
        const float4 a0 = *reinterpret_cast<const float4*>(&zT[d][ty * 8]);
        const float4 a1 = *reinterpret_cast<const float4*>(&zT[d][ty * 8 + 4]);
        const float za[8] = {a0.x, a0.y, a0.z, a0.w, a1.x, a1.y, a1.z, a1.w};
        // eb: 4 quads at 16B lane stride (codes tx*4+m*128)
        float eb[16];
#pragma unroll
        for (int m = 0; m < 4; ++m) {
          const float4 e =
              *reinterpret_cast<const float4*>(&eT[buf][dd][m * 128 + tx * 4]);
          eb[m * 4 + 0] = e.x;
          eb[m * 4 + 1] = e.y;
          eb[m * 4 + 2] = e.z;
          eb[m * 4 + 3] = e.w;
        }
        // single fp32 FMA chain per (row, code), ascending d
#pragma unroll
        for (int i = 0; i < 8; ++i)
#pragma unroll
          for (int j = 0; j < 16; ++j) acc[i][j] = fmaf(za[i], eb[j], acc[i][j]);
      }
    }

    // running argmin: dist = fl32(S - 2*fl32(dot)); ascending code order
#pragma unroll
    for (int i = 0; i < 8; ++i)
#pragma unroll
      for (int m = 0; m < 4; ++m)
#pragma unroll
        for (int s = 0; s < 4; ++s) {
          const float dist = fmaf(-2.0f, acc[i][m * 4 + s], Srow[i]);
          const int code = c0 + m * 128 + tx * 4 + s;
          if (dist < best[i]) {  // strict <: earliest index wins
            best[i] = dist;
            bidx[i] = code;
          }
        }
  }

  // reduce across the 32 tx lanes (xor masks stay within the 32-lane half)
#pragma unroll
  for (int i = 0; i < 8; ++i) {
    float bv = best[i];
    int bi = bidx[i];
#pragma unroll
    for (int m = 1; m < 32; m <<= 1) {
      float ov = __shfl_xor(bv, m, 64);
      int oi = __shfl_xor(bi, m, 64);
      if (ov < bv || (ov == bv && oi < bi)) { bv = ov; bi = oi; }
    }
    if (tx == 0) {
      int row = row0 + ty * 8 + i;
      idx_i[row] = bi;
      idx_f[row] = (float)bi;
    }
  }
}

// ---- gather z_q = emb[idx], partial sums of (z_q - z)^2 ----
__global__ void gather_kernel(const float* __restrict__ z,
                              const float* __restrict__ emb,
                              const int* __restrict__ idx,
                              float* __restrict__ zq,
                              float* __restrict__ partial) {
  const int w = threadIdx.x >> 6;
  const int lane = threadIdx.x & 63;
  const int row = blockIdx.x * 4 + w;
  const int k = idx[row];
  const float4 e = reinterpret_cast<const float4*>(emb)[(size_t)k * (ND / 4) + lane];
  const float4 zv = reinterpret_cast<const float4*>(z)[(size_t)row * (ND / 4) + lane];
  reinterpret_cast<float4*>(zq)[(size_t)row * (ND / 4) + lane] = e;
  const float dx = e.x - zv.x, dy = e.y - zv.y, dz = e.z - zv.z, dw = e.w - zv.w;
  float s = dx * dx + dy * dy + dz * dz + dw * dw;
#pragma unroll
  for (int off = 32; off; off >>= 1) s += __shfl_down(s, off, 64);
  __shared__ float sm[4];
  if (lane == 0) sm[w] = s;
  __syncthreads();
  if (threadIdx.x == 0) partial[blockIdx.x] = sm[0] + sm[1] + sm[2] + sm[3];
}

// ---- deterministic final loss reduction ----
__global__ void loss_kernel(const float* __restrict__ partial, int n,
                            float* __restrict__ out_loss) {
  double s = 0.0;
  for (int i = threadIdx.x; i < n; i += 256) s += (double)partial[i];
  __shared__ double sm[256];
  sm[threadIdx.x] = s;
  __syncthreads();
  for (int st = 128; st; st >>= 1) {
    if (threadIdx.x < st) sm[threadIdx.x] += sm[threadIdx.x + st];
    __syncthreads();
  }
  if (threadIdx.x == 0) {
    float loss = (float)(0.25 * sm[0] / (double)((size_t)NB * ND));
    out_loss[0] = loss;  // vq_loss
    out_loss[1] = loss;  // commitment loss (same forward value)
  }
}

}  // namespace

extern "C" void kernel_launch(void* const* d_in, const int* in_sizes, int n_in,
                              void* d_out, int out_size, void* d_ws, size_t ws_size,
                              hipStream_t stream) {
  const float* z = (const float*)d_in[0];
  const float* emb = (const float*)d_in[1];
  float* out = (float*)d_out;
  float* zq = out;
  float* loss = out + (size_t)NB * ND;
  float* idx_f = out + (size_t)NB * ND + 2;

  int* idx_i = (int*)d_ws;
  float* sz = (float*)((char*)d_ws + (size_t)NB * 4);
  float* partial = (float*)((char*)d_ws + (size_t)NB * 4 * 2);

  sz_kernel<<<NB / 4, 256, 0, stream>>>(z, sz);
  argmin_kernel<<<NB / BM, 256, 0, stream>>>(z, emb, sz, idx_i, idx_f);
  gather_kernel<<<NB / 4, 256, 0, stream>>>(z, emb, idx_i, zq, partial);
  loss_kernel<<<1, 256, 0, stream>>>(partial, NB / 4, loss);
}

// Round 4
// 1808.142 us; speedup vs baseline: 1.2616x; 1.0001x over previous
//
#include <hip/hip_runtime.h>

// VectorQuantizer: B=32768, K=8192, D=256, fp32.
// out layout (flat float): z_q [B*D], vq_loss [1], commit [1], indices-as-float [B]
// ws layout: idx_i int[B] | s_z float[B] | partial float[B/4]
//
// Numerics (verified round 2): ref dist = fl32(S - 2*fl32(dot)), dot = single
// fp32 FMA chain ascending in d per (row,code); ties (frequent — dist is
// quantized at ulp(||z||^2~256) = 3e-5) resolved by FIRST index.
//
// Round-4 change: round 3 spilled (VGPR capped at 128 = 4 waves/EU target,
// WRITE_SIZE 57 MB of scratch). Pin occupancy to 2 waves/EU via
// amdgpu_waves_per_eu(2,2) -> VGPR budget 256 for the ~195 live regs
// (acc[8][16]=128 + operands/best/addressing). LDS stays 80 KB -> exactly
// 2 blocks/CU (8 waves/CU), now spill-free.

namespace {
constexpr int NB = 32768;
constexpr int NK = 8192;
constexpr int ND = 256;
constexpr int BM = 64;    // rows per block
constexpr int BN = 512;   // codes per chunk
constexpr int BK = 4;     // d per stage

// ---- S[row] = ||z_row||^2 ----
__global__ void sz_kernel(const float* __restrict__ z, float* __restrict__ sz) {
  const int row = blockIdx.x * 4 + (threadIdx.x >> 6);
  const int lane = threadIdx.x & 63;
  const float4 v = reinterpret_cast<const float4*>(z)[(size_t)row * (ND / 4) + lane];
  float s = v.x * v.x + v.y * v.y + v.z * v.z + v.w * v.w;
#pragma unroll
  for (int off = 32; off; off >>= 1) s += __shfl_down(s, off, 64);
  if (lane == 0) sz[row] = s;
}

// ---- argmin over codes of fl32(S - 2*fl32(z.e)), first-index tie-break ----
__global__ __launch_bounds__(256)
__attribute__((amdgpu_waves_per_eu(2, 2)))
void argmin_kernel(
    const float* __restrict__ z, const float* __restrict__ emb,
    const float* __restrict__ sz, int* __restrict__ idx_i,
    float* __restrict__ idx_f) {
  __shared__ float zT[ND][BM];       // 64 KB, persistent z^T tile
  __shared__ float eT[2][BK][BN];    // 16 KB, double-buffered e^T chunk

  const int tid = threadIdx.x;
  const int tx = tid & 31;   // code group
  const int ty = tid >> 5;   // row group (0..7)
  const int row0 = blockIdx.x * BM;

  // stage zT (transpose z[row][d] -> zT[d][row]); coalesced loads, one-time
  {
    const float4* z4 = reinterpret_cast<const float4*>(z) + (size_t)row0 * (ND / 4);
#pragma unroll
    for (int it = 0; it < 16; ++it) {
      int fi = it * 256 + tid;  // float4 index in tile (64 rows * 64 f4/row)
      int r = fi >> 6;
      int dq = fi & 63;
      float4 v = z4[(size_t)r * (ND / 4) + dq];
      zT[dq * 4 + 0][r] = v.x;
      zT[dq * 4 + 1][r] = v.y;
      zT[dq * 4 + 2][r] = v.z;
      zT[dq * 4 + 3][r] = v.w;
    }
  }

  float Srow[8];
#pragma unroll
  for (int i = 0; i < 8; ++i) Srow[i] = sz[row0 + ty * 8 + i];

  float best[8];
  int bidx[8];
#pragma unroll
  for (int i = 0; i < 8; ++i) { best[i] = 3.4e38f; bidx[i] = 0; }

  const float4* e4 = reinterpret_cast<const float4*>(emb);
  const int cA = tid;        // stages code rows tid and tid+256
  const int cB = tid + 256;

  for (int n = 0; n < NK / BN; ++n) {
    const int c0 = n * BN;
    float acc[8][16];
#pragma unroll
    for (int i = 0; i < 8; ++i)
#pragma unroll
      for (int j = 0; j < 16; ++j) acc[i][j] = 0.f;

    // preload dk=0 slice (1 float4 per staged code row)
    float4 p0 = e4[(size_t)(c0 + cA) * (ND / 4) + 0];
    float4 p1 = e4[(size_t)(c0 + cB) * (ND / 4) + 0];

    for (int dk = 0; dk < ND / BK; ++dk) {
      const int buf = dk & 1;
      // transposed store: eT[dd][code]; lane-consecutive addresses -> no conflicts
      eT[buf][0][cA] = p0.x;
      eT[buf][1][cA] = p0.y;
      eT[buf][2][cA] = p0.z;
      eT[buf][3][cA] = p0.w;
      eT[buf][0][cB] = p1.x;
      eT[buf][1][cB] = p1.y;
      eT[buf][2][cB] = p1.z;
      eT[buf][3][cB] = p1.w;
      if (dk + 1 < ND / BK) {  // prefetch next slice; L2 retains the 64B lines
        p0 = e4[(size_t)(c0 + cA) * (ND / 4) + dk + 1];
        p1 = e4[(size_t)(c0 + cB) * (ND / 4) + dk + 1];
      }
      __syncthreads();  // dbuf: single barrier per stage is sufficient
#pragma unroll
      for (int dd = 0; dd < BK; ++dd) {
        const int d = dk * BK + dd;
        // za: 8 rows, broadcast across tx lanes (same address -> conflict-free)
        const float4 a0 = *reinterpret_cast<const float4*>(&zT[d][ty * 8]);
        const float4 a1 = *reinterpret_cast<const float4*>(&zT[d][ty * 8 + 4]);
        const float za[8] = {a0.x, a0.y, a0.z, a0.w, a1.x, a1.y, a1.z, a1.w};
        // eb: 4 quads at 16B lane stride (codes tx*4+m*128) -> 2-way = free
        float eb[16];
#pragma unroll
        for (int m = 0; m < 4; ++m) {
          const float4 e =
              *reinterpret_cast<const float4*>(&eT[buf][dd][m * 128 + tx * 4]);
          eb[m * 4 + 0] = e.x;
          eb[m * 4 + 1] = e.y;
          eb[m * 4 + 2] = e.z;
          eb[m * 4 + 3] = e.w;
        }
        // single fp32 FMA chain per (row, code), ascending d
#pragma unroll
        for (int i = 0; i < 8; ++i)
#pragma unroll
          for (int j = 0; j < 16; ++j) acc[i][j] = fmaf(za[i], eb[j], acc[i][j]);
      }
    }

    // running argmin: dist = fl32(S - 2*fl32(dot)); ascending code order
#pragma unroll
    for (int i = 0; i < 8; ++i)
#pragma unroll
      for (int m = 0; m < 4; ++m)
#pragma unroll
        for (int s = 0; s < 4; ++s) {
          const float dist = fmaf(-2.0f, acc[i][m * 4 + s], Srow[i]);
          const int code = c0 + m * 128 + tx * 4 + s;
          if (dist < best[i]) {  // strict <: earliest index wins
            best[i] = dist;
            bidx[i] = code;
          }
        }
  }

  // reduce across the 32 tx lanes (xor masks stay within the 32-lane half)
#pragma unroll
  for (int i = 0; i < 8; ++i) {
    float bv = best[i];
    int bi = bidx[i];
#pragma unroll
    for (int m = 1; m < 32; m <<= 1) {
      float ov = __shfl_xor(bv, m, 64);
      int oi = __shfl_xor(bi, m, 64);
      if (ov < bv || (ov == bv && oi < bi)) { bv = ov; bi = oi; }
    }
    if (tx == 0) {
      int row = row0 + ty * 8 + i;
      idx_i[row] = bi;
      idx_f[row] = (float)bi;
    }
  }
}

// ---- gather z_q = emb[idx], partial sums of (z_q - z)^2 ----
__global__ void gather_kernel(const float* __restrict__ z,
                              const float* __restrict__ emb,
                              const int* __restrict__ idx,
                              float* __restrict__ zq,
                              float* __restrict__ partial) {
  const int w = threadIdx.x >> 6;
  const int lane = threadIdx.x & 63;
  const int row = blockIdx.x * 4 + w;
  const int k = idx[row];
  const float4 e = reinterpret_cast<const float4*>(emb)[(size_t)k * (ND / 4) + lane];
  const float4 zv = reinterpret_cast<const float4*>(z)[(size_t)row * (ND / 4) + lane];
  reinterpret_cast<float4*>(zq)[(size_t)row * (ND / 4) + lane] = e;
  const float dx = e.x - zv.x, dy = e.y - zv.y, dz = e.z - zv.z, dw = e.w - zv.w;
  float s = dx * dx + dy * dy + dz * dz + dw * dw;
#pragma unroll
  for (int off = 32; off; off >>= 1) s += __shfl_down(s, off, 64);
  __shared__ float sm[4];
  if (lane == 0) sm[w] = s;
  __syncthreads();
  if (threadIdx.x == 0) partial[blockIdx.x] = sm[0] + sm[1] + sm[2] + sm[3];
}

// ---- deterministic final loss reduction ----
__global__ void loss_kernel(const float* __restrict__ partial, int n,
                            float* __restrict__ out_loss) {
  double s = 0.0;
  for (int i = threadIdx.x; i < n; i += 256) s += (double)partial[i];
  __shared__ double sm[256];
  sm[threadIdx.x] = s;
  __syncthreads();
  for (int st = 128; st; st >>= 1) {
    if (threadIdx.x < st) sm[threadIdx.x] += sm[threadIdx.x + st];
    __syncthreads();
  }
  if (threadIdx.x == 0) {
    float loss = (float)(0.25 * sm[0] / (double)((size_t)NB * ND));
    out_loss[0] = loss;  // vq_loss
    out_loss[1] = loss;  // commitment loss (same forward value)
  }
}

}  // namespace

extern "C" void kernel_launch(void* const* d_in, const int* in_sizes, int n_in,
                              void* d_out, int out_size, void* d_ws, size_t ws_size,
                              hipStream_t stream) {
  const float* z = (const float*)d_in[0];
  const float* emb = (const float*)d_in[1];
  float* out = (float*)d_out;
  float* zq = out;
  float* loss = out + (size_t)NB * ND;
  float* idx_f = out + (size_t)NB * ND + 2;

  int* idx_i = (int*)d_ws;
  float* sz = (float*)((char*)d_ws + (size_t)NB * 4);
  float* partial = (float*)((char*)d_ws + (size_t)NB * 4 * 2);

  sz_kernel<<<NB / 4, 256, 0, stream>>>(z, sz);
  argmin_kernel<<<NB / BM, 256, 0, stream>>>(z, emb, sz, idx_i, idx_f);
  gather_kernel<<<NB / 4, 256, 0, stream>>>(z, emb, idx_i, zq, partial);
  loss_kernel<<<1, 256, 0, stream>>>(partial, NB / 4, loss);
}